// Round 15
// baseline (1119.087 us; speedup 1.0000x reference)
//
#include <hip/hip_runtime.h>
#include <math.h>

// KimiK2 MoE gate. Round 15: balanced 8x8 microtile. Wave = 16 tok x 256 exp
// (lane: p=lane>>5 token-half, e5=lane&31 -> experts e5+32j). 4 waves/block,
// grid 256 = 1 block/CU. w+x staged via async global_load_lds (dbuf, r11
// swizzle); 16 ds_reads per 256 FMA-instr; A/B chunk pipeline in registers.
// Semantics bit-identical to r7/9/11 (ties -> higher index).
// Output: [T*8 indices as float][T*8 weights].

#define HH 7168
#define EE 256
#define BMT 64
#define BK 32
#define NTH 256
#define NT (HH / BK)

typedef float v4f __attribute__((ext_vector_type(4)));

struct SMem {
    union {
        float wbuf[2][EE * BK];   // 64 KB (2 x 32 KB w slices)
        float logits[BMT][EE];    // 64 KB
    } u;
    float xbuf[2][BMT * BK];      // 16 KB (2 x 8 KB x slices)
    float bias[EE];
};

__device__ __forceinline__ void gl16(const void* g, void* l) {
    __builtin_amdgcn_global_load_lds(
        (__attribute__((address_space(1))) const void*)g,
        (__attribute__((address_space(3))) void*)l, 16, 0, 0);
}

#define LOADW(dst, wl, q) do {                                               \
    const float* wp_ = (wl) + e5 * BK + (((q) ^ e3) << 2);                   \
    dst[0] = *(const v4f*)(wp_ +   0 * BK);                                  \
    dst[1] = *(const v4f*)(wp_ +  32 * BK);                                  \
    dst[2] = *(const v4f*)(wp_ +  64 * BK);                                  \
    dst[3] = *(const v4f*)(wp_ +  96 * BK);                                  \
    dst[4] = *(const v4f*)(wp_ + 128 * BK);                                  \
    dst[5] = *(const v4f*)(wp_ + 160 * BK);                                  \
    dst[6] = *(const v4f*)(wp_ + 192 * BK);                                  \
    dst[7] = *(const v4f*)(wp_ + 224 * BK); } while (0)

#define LOADX(dst, xl, q) do { _Pragma("unroll")                             \
    for (int t_ = 0; t_ < 8; ++t_)                                           \
        dst[t_] = *(const v4f*)((xl) + t_ * BK + (q) * 4); } while (0)

#define FMAB(xr, wr) do { _Pragma("unroll")                                  \
    for (int t_ = 0; t_ < 8; ++t_) { _Pragma("unroll")                       \
        for (int c_ = 0; c_ < 4; ++c_) {                                     \
            const float xs_ = xr[t_][c_]; _Pragma("unroll")                  \
            for (int j_ = 0; j_ < 8; ++j_)                                   \
                acc[t_][j_] = fmaf(xs_, wr[j_][c_], acc[t_][j_]);            \
        } } } while (0)

__global__ __launch_bounds__(NTH, 1)
void moe_gate(const float* __restrict__ x, const float* __restrict__ w,
              const float* __restrict__ bias, float* __restrict__ out, int T) {
    __shared__ SMem sm;
    const int tid = threadIdx.x;
    const int bm = blockIdx.x * BMT;
    sm.bias[tid] = bias[tid];
    const int lane = tid & 63;
    const int wv = __builtin_amdgcn_readfirstlane(tid >> 6);
    const int p = lane >> 5;        // token half within wave
    const int e5 = lane & 31;       // expert lane: experts e5 + 32j
    const int e3 = e5 & 7;          // w swizzle key (row&7 of read rows)
    const int l3 = (lane >> 3) & 7, l7 = lane & 7;  // staging roles

    // w staging: wave wv stages rows [wv*64, wv*64+64), 8 gl16/thread
    // invariant: stored[slot] = orig[slot ^ (row&7)]
    const float* wsrc = w + (size_t)(wv * 64 + l3) * HH + ((l7 ^ l3) << 2);
    float* const wdst0 = &sm.u.wbuf[0][wv * 64 * BK];
    float* const wdst1 = &sm.u.wbuf[1][wv * 64 * BK];
    // x staging: wave wv stages its own 16 tokens, 2 gl16/thread (linear)
    const float* xsrc = x + (size_t)(bm + wv * 16 + l3) * HH + (l7 << 2);
    float* const xdst0 = &sm.xbuf[0][wv * 16 * BK];
    float* const xdst1 = &sm.xbuf[1][wv * 16 * BK];

    float acc[8][8];
    #pragma unroll
    for (int t = 0; t < 8; ++t)
        #pragma unroll
        for (int j = 0; j < 8; ++j) acc[t][j] = 0.f;

    // prologue: stage slice 0 into buffer 0
    #pragma unroll
    for (int p_ = 0; p_ < 8; ++p_)
        gl16(wsrc + (size_t)p_ * 8 * HH, wdst0 + p_ * 8 * BK);
    #pragma unroll
    for (int i_ = 0; i_ < 2; ++i_)
        gl16(xsrc + (size_t)i_ * 8 * HH, xdst0 + i_ * 8 * BK);
    __syncthreads();

    for (int ts = 0; ts < NT; ++ts) {
        const int b = ts & 1;
        if (ts + 1 < NT) {
            const int k1 = (ts + 1) * BK;
            float* wd = b ? wdst0 : wdst1;
            float* xd = b ? xdst0 : xdst1;
            #pragma unroll
            for (int p_ = 0; p_ < 8; ++p_)
                gl16(wsrc + (size_t)p_ * 8 * HH + k1, wd + p_ * 8 * BK);
            #pragma unroll
            for (int i_ = 0; i_ < 2; ++i_)
                gl16(xsrc + (size_t)i_ * 8 * HH + k1, xd + i_ * 8 * BK);
        }
        const float* wl = sm.u.wbuf[b];
        const float* xl = &sm.xbuf[b][(wv * 16 + p * 8) * BK];

        v4f wA[8], wB[8], xA[8], xB[8];
        LOADW(wA, wl, 0); LOADX(xA, xl, 0);
        LOADW(wB, wl, 1); LOADX(xB, xl, 1); FMAB(xA, wA);   // q=0
        LOADW(wA, wl, 2); LOADX(xA, xl, 2); FMAB(xB, wB);   // q=1
        LOADW(wB, wl, 3); LOADX(xB, xl, 3); FMAB(xA, wA);   // q=2
        LOADW(wA, wl, 4); LOADX(xA, xl, 4); FMAB(xB, wB);   // q=3
        LOADW(wB, wl, 5); LOADX(xB, xl, 5); FMAB(xA, wA);   // q=4
        LOADW(wA, wl, 6); LOADX(xA, xl, 6); FMAB(xB, wB);   // q=5
        LOADW(wB, wl, 7); LOADX(xB, xl, 7); FMAB(xA, wA);   // q=6
        FMAB(xB, wB);                                        // q=7
        __syncthreads();  // staged slice landed; all waves done with buffer
    }

    // dump logits (aliases wbuf; all w reads complete after barrier)
    #pragma unroll
    for (int t = 0; t < 8; ++t)
        #pragma unroll
        for (int j = 0; j < 8; ++j)
            sm.u.logits[wv * 16 + p * 8 + t][e5 + 32 * j] = acc[t][j];
    __syncthreads();

    // ---- routing: round-7 verbatim (ties -> higher index) ----
    for (int tt = wv; tt < BMT; tt += 4) {
        const int gt = bm + tt;
        float4 lg = *(const float4*)&sm.u.logits[tt][lane * 4];
        float lgv[4] = {lg.x, lg.y, lg.z, lg.w};
        float s[4], sc[4], m[4];
        #pragma unroll
        for (int j = 0; j < 4; ++j) {
            float e = (float)exp(-(double)lgv[j]);
            float u = __fadd_rn(1.0f, e);
            s[j] = __fdiv_rn(1.0f, u);
            sc[j] = __fadd_rn(s[j], sm.bias[lane * 4 + j]);
        }
        float a1 = fmaxf(sc[0], sc[1]), a2 = fminf(sc[0], sc[1]);
        if (sc[2] > a1) { a2 = a1; a1 = sc[2]; } else a2 = fmaxf(a2, sc[2]);
        if (sc[3] > a1) { a2 = a1; a1 = sc[3]; } else a2 = fmaxf(a2, sc[3]);
        #pragma unroll
        for (int off = 1; off <= 4; off <<= 1) {
            float b1 = __shfl_xor(a1, off);
            float b2 = __shfl_xor(a2, off);
            float m1 = fmaxf(a1, b1);
            float m2 = fmaxf(fminf(a1, b1), (a1 >= b1) ? a2 : b2);
            a1 = m1; a2 = m2;
        }
        float gsc = __fadd_rn(a1, a2);
        float gsv[8];
        #pragma unroll
        for (int g = 0; g < 8; ++g) gsv[g] = __shfl(gsc, g * 8);
        int gm = lane >> 3;
        int rank = 0;
        #pragma unroll
        for (int hh = 0; hh < 8; ++hh)
            rank += (gsv[hh] > gsv[gm]) || (gsv[hh] == gsv[gm] && hh > gm);
        bool selg = rank < 4;
        #pragma unroll
        for (int j = 0; j < 4; ++j) m[j] = selg ? sc[j] : 0.0f;

        float selw = 0.f; int seli = 0;
        #pragma unroll
        for (int k = 0; k < 8; ++k) {
            float bv = m[0]; int bj = 0;
            #pragma unroll
            for (int j = 1; j < 4; ++j)
                if (m[j] >= bv) { bv = m[j]; bj = j; }
            float v = bv; int ii = lane * 4 + bj;
            #pragma unroll
            for (int off = 1; off < 64; off <<= 1) {
                float ov = __shfl_xor(v, off);
                int oi = __shfl_xor(ii, off);
                if (ov > v || (ov == v && oi > ii)) { v = ov; ii = oi; }
            }
            int oj = ii & 3, ol = ii >> 2;
            float cand = (oj == 0) ? s[0] : (oj == 1) ? s[1]
                       : (oj == 2) ? s[2] : s[3];
            float wgt = __shfl(cand, ol);
            if (lane == k) { seli = ii; selw = wgt; }
            if (lane == ol) {
                if (oj == 0) m[0] = -1e30f;
                else if (oj == 1) m[1] = -1e30f;
                else if (oj == 2) m[2] = -1e30f;
                else m[3] = -1e30f;
            }
        }
        float wk[8];
        #pragma unroll
        for (int k = 0; k < 8; ++k) wk[k] = __shfl(selw, k);
        float denom = __fadd_rn(
            __fadd_rn(__fadd_rn(wk[0], wk[1]), __fadd_rn(wk[2], wk[3])),
            __fadd_rn(__fadd_rn(wk[4], wk[5]), __fadd_rn(wk[6], wk[7])));
        denom = __fadd_rn(denom, 1e-20f);
        if (lane < 8) {
            out[(size_t)gt * 8 + lane] = (float)seli;
            out[(size_t)T * 8 + (size_t)gt * 8 + lane] =
                __fmul_rn(__fdiv_rn(selw, denom), 2.5f);
        }
    }
}

extern "C" void kernel_launch(void* const* d_in, const int* in_sizes, int n_in,
                              void* d_out, int out_size, void* d_ws, size_t ws_size,
                              hipStream_t stream) {
    const float* x    = (const float*)d_in[0];
    const float* w    = (const float*)d_in[1];
    const float* bias = (const float*)d_in[2];
    float* out = (float*)d_out;
    const int T = in_sizes[0] / HH; // 16384
    moe_gate<<<T / BMT, NTH, 0, stream>>>(x, w, bias, out, T);
}